// Round 4
// baseline (29030.569 us; speedup 1.0000x reference)
//
#include <hip/hip_runtime.h>
#include <hip/hip_bf16.h>
#include <math.h>

#define BATCH 4
#define SEQ   2048
#define DIM   1024
#define MROWS (SEQ*BATCH)          // 8192
#define BIGN  ((size_t)MROWS*DIM)  // 8388608 floats per buffer

// ---------------- chunked scan for r_t = dec*r + k*v,  ret = q*r --------------
__global__ __launch_bounds__(256) void scan_a(const float* __restrict__ K,
    const float* __restrict__ V, const float* __restrict__ dec_p,
    float* __restrict__ E)
{
  int id  = blockIdx.x*256 + threadIdx.x;   // 0..262143
  int c   = id >> 12;
  int rem = id & 4095;
  int b   = rem >> 10;
  int dc  = rem & 1023;
  float dec = dec_p[dc >> 6];
  size_t base = ((size_t)b*SEQ + (size_t)c*32)*DIM + dc;
  float r = 0.f;
  #pragma unroll 4
  for (int i = 0; i < 32; ++i) {
    float kv = K[base + (size_t)i*DIM] * V[base + (size_t)i*DIM];
    r = fmaf(dec, r, kv);
  }
  E[(size_t)c*4096 + rem] = r;
}

__global__ __launch_bounds__(256) void scan_b(const float* __restrict__ E,
    const float* __restrict__ dec_p, float* __restrict__ carry)
{
  int id = blockIdx.x*256 + threadIdx.x;    // 0..4095
  int dc = id & 1023;
  float dec = dec_p[dc >> 6];
  float d2 = dec*dec, d4 = d2*d2, d8 = d4*d4, d16 = d8*d8, d32 = d16*d16;
  float r = 0.f;
  #pragma unroll 1
  for (int c = 0; c < 64; ++c) {
    carry[(size_t)c*4096 + id] = r;
    r = fmaf(d32, r, E[(size_t)c*4096 + id]);
  }
}

__global__ __launch_bounds__(256) void scan_c(const float* __restrict__ Q,
    const float* __restrict__ K, const float* __restrict__ V,
    const float* __restrict__ dec_p, const float* __restrict__ carry,
    float* __restrict__ ret)
{
  int id  = blockIdx.x*256 + threadIdx.x;
  int c   = id >> 12;
  int rem = id & 4095;
  int b   = rem >> 10;
  int dc  = rem & 1023;
  float dec = dec_p[dc >> 6];
  size_t base = ((size_t)b*SEQ + (size_t)c*32)*DIM + dc;
  float r = carry[(size_t)c*4096 + rem];
  #pragma unroll 1
  for (int i = 0; i < 32; ++i) {
    int t = c*32 + i;
    float kv = K[base + (size_t)i*DIM] * V[base + (size_t)i*DIM];
    r = fmaf(dec, r, kv);
    ret[((size_t)t*BATCH + b)*DIM + dc] = Q[base + (size_t)i*DIM] * r;
  }
}

// ---------------- fp32 tiled GEMM: C[m,n] = sum_k X[m,k]*W[n,k] (+bias) -------
// MODE 0: C = XW^T + bias
// MODE 1: g = sigmoid(XW^T + bias) -> C;  u_out = (1-g)*inp
// MODE 2: C += XW^T
// MODE 3: outf[b,t,n] = XW^T + bias   (m = t*4+b scatter), float32 output
// MODE 4: C = XW^T
#define GM 64
#define GN 64
#define GK 32
#define LDA 68

template<int MODE>
__global__ __launch_bounds__(256) void gemm_k(
    const float* __restrict__ X, const float* __restrict__ W,
    const float* __restrict__ bias, float* __restrict__ C,
    const float* __restrict__ inp, float* __restrict__ u_out,
    float* __restrict__ outf)
{
  __shared__ float Xs[GK][LDA];
  __shared__ float Ws[GK][LDA];
  const int tid = threadIdx.x;
  const int m0 = blockIdx.y * GM;
  const int n0 = blockIdx.x * GN;
  const int tx = tid & 15, ty = tid >> 4;
  float acc[4][4] = {};
  #pragma unroll 1
  for (int kb = 0; kb < DIM; kb += GK) {
    #pragma unroll
    for (int h = 0; h < 2; ++h) {
      int idx = tid + h*256;
      int row = idx >> 3;        // 0..63
      int kc  = (idx & 7) << 2;  // 0,4,...,28
      float4 xv = *(const float4*)(X + (size_t)(m0+row)*DIM + kb + kc);
      Xs[kc+0][row] = xv.x; Xs[kc+1][row] = xv.y;
      Xs[kc+2][row] = xv.z; Xs[kc+3][row] = xv.w;
      float4 wv = *(const float4*)(W + (size_t)(n0+row)*DIM + kb + kc);
      Ws[kc+0][row] = wv.x; Ws[kc+1][row] = wv.y;
      Ws[kc+2][row] = wv.z; Ws[kc+3][row] = wv.w;
    }
    __syncthreads();
    #pragma unroll
    for (int kk = 0; kk < GK; ++kk) {
      float4 a = *(const float4*)&Xs[kk][ty << 2];
      float4 w = *(const float4*)&Ws[kk][tx << 2];
      float av[4] = {a.x, a.y, a.z, a.w};
      float wv[4] = {w.x, w.y, w.z, w.w};
      #pragma unroll
      for (int i = 0; i < 4; ++i)
        #pragma unroll
        for (int j = 0; j < 4; ++j)
          acc[i][j] = fmaf(av[i], wv[j], acc[i][j]);
    }
    __syncthreads();
  }
  float bj[4];
  #pragma unroll
  for (int j = 0; j < 4; ++j)
    bj[j] = (MODE == 0 || MODE == 1 || MODE == 3) ? bias[n0 + (tx<<2) + j] : 0.f;
  #pragma unroll
  for (int i = 0; i < 4; ++i) {
    int m = m0 + (ty<<2) + i;
    #pragma unroll
    for (int j = 0; j < 4; ++j) {
      int n = n0 + (tx<<2) + j;
      size_t off = (size_t)m*DIM + n;
      float vv = acc[i][j] + bj[j];
      if (MODE == 2) vv += C[off];
      if (MODE == 1) {
        float gv = 1.f/(1.f + expf(-vv));
        C[off] = gv;
        u_out[off] = (1.f - gv) * inp[off];
      } else if (MODE == 3) {
        outf[((size_t)(m & 3)*SEQ + (size_t)(m >> 2))*DIM + n] = vv;
      } else {
        C[off] = vv;
      }
    }
  }
}

// ---------------- sequential recurrence: s_t = tanh((g_t*s_{t-1})@A^T + d_t) --
// 32 blocks x 4 waves. A slice in REGISTERS (row per 8-lane group, k 8-way
// split). Cross-block traffic via L3 only: relaxed agent atomics (sc-bit
// bypass), release atomicAdd publish, relaxed spin. No fences, no barriers
// inside the step loop.
#define RG  32     // workgroups; each owns RR rows of A
#define RR  32

__global__ __launch_bounds__(256, 1) void recur_k(
    const float* __restrict__ A, const float* __restrict__ g,
    const float* __restrict__ dpre, float* __restrict__ s,
    int* __restrict__ ctr)
{
  // per-wave private copy of x = g*s, slice-padded: slice stride 132 dwords
  // (132 mod 32 = 4 -> the 8 k-slices start at banks 0,4,...,28: the 8-address
  // broadcast read covers all 32 banks conflict-free)
  __shared__ __align__(16) float xs[4][4224];   // 67.5 KB
  const int tid  = threadIdx.x;
  const int w    = tid >> 6;        // wave -> 8 rows
  const int ln   = tid & 63;
  const int r    = ln >> 3;         // row within wave's 8
  const int ks   = ln & 7;          // k-slice (128 floats)
  const int base = blockIdx.x * RR;
  const int grow = base + 8*w + r;  // global output row
  float* xw = xs[w];

  // stage this lane's A fragment into registers: k in [ks*128, ks*128+128)
  float4 areg[32];
  #pragma unroll
  for (int j = 0; j < 32; ++j)
    areg[j] = *(const float4*)(A + (size_t)grow*DIM + ks*128 + 4*j);

  #pragma unroll 1
  for (int t = 0; t < SEQ; ++t) {
    // consumer-private prefetches (independent of the flag -> hide under spin)
    float dval = dpre[(size_t)(t*4 + (ks & 3))*DIM + grow];
    float acc[4] = {0.f, 0.f, 0.f, 0.f};

    if (t > 0) {
      const unsigned long long* g2 =
          (const unsigned long long*)(g + (size_t)t*BATCH*DIM);
      const unsigned long long* s2 =
          (const unsigned long long*)(s + (size_t)(t-1)*BATCH*DIM);
      // prefetch g (L2-cached) before spinning
      unsigned long long gpre[32];
      #pragma unroll
      for (int j = 0; j < 32; ++j) gpre[j] = g2[j*64 + ln];

      // spin until all 128 waves published step t-1
      int guard = 0;
      while (__hip_atomic_load(ctr + (t-1), __ATOMIC_RELAXED,
                               __HIP_MEMORY_SCOPE_AGENT) < 4*RG) {
        if (++guard > (1 << 26)) break;   // anti-hang bailout
      }
      __asm__ __volatile__("" ::: "memory");

      // stage x = g * s[t-1] into this wave's LDS copy (bypass loads of s)
      #pragma unroll
      for (int j = 0; j < 32; ++j) {
        int f = j*64 + ln;            // float2 flat index 0..2047
        int b = f >> 9;
        int p = f & 511;
        int ksf  = p >> 6;
        int i4   = (p >> 1) & 31;
        int half = p & 1;
        union { unsigned long long u; float fv[2]; } sv, gv;
        sv.u = __hip_atomic_load(s2 + f, __ATOMIC_RELAXED,
                                 __HIP_MEMORY_SCOPE_AGENT);
        gv.u = gpre[j];
        int off = (b*8 + ksf)*132 + 4*i4 + 2*half;
        *(float2*)(xw + off) = make_float2(gv.fv[0]*sv.fv[0],
                                           gv.fv[1]*sv.fv[1]);
      }
      // wave-internal LDS RAW only -> compiler's lgkmcnt handles it; no barrier

      // matvec: acc[b] = sum_k A[grow][k] * x[b][k]  (this lane: its k-slice)
      #pragma unroll
      for (int b = 0; b < 4; ++b) {
        const float* xb = xw + (b*8 + ks)*132;
        #pragma unroll
        for (int j = 0; j < 32; ++j) {
          float4 xv = *(const float4*)(xb + 4*j);
          acc[b] = fmaf(areg[j].x, xv.x,
                   fmaf(areg[j].y, xv.y,
                   fmaf(areg[j].z, xv.z,
                   fmaf(areg[j].w, xv.w, acc[b]))));
        }
      }
      // reduce across the 8 k-slice lanes of this row (in-wave)
      #pragma unroll
      for (int m = 1; m <= 4; m <<= 1) {
        #pragma unroll
        for (int b = 0; b < 4; ++b) acc[b] += __shfl_xor(acc[b], m, 64);
      }
    }

    // lanes ks<4 own batch b=ks for this row: activation + write-through store
    if (ks < 4) {
      float val = tanhf(acc[ks] + dval);
      __hip_atomic_store(s + (size_t)(t*4 + ks)*DIM + grow, val,
                         __ATOMIC_RELAXED, __HIP_MEMORY_SCOPE_AGENT);
    }
    // publish: release waits this wave's vmcnt; no dirty L2 lines exist
    if (ln == 0)
      __hip_atomic_fetch_add(ctr + t, 1, __ATOMIC_RELEASE,
                             __HIP_MEMORY_SCOPE_AGENT);
  }
}

// ------------------------------------------------------------------------------
extern "C" void kernel_launch(void* const* d_in, const int* in_sizes, int n_in,
                              void* d_out, int out_size, void* d_ws, size_t ws_size,
                              hipStream_t stream)
{
  (void)in_sizes; (void)n_in; (void)out_size;
  const float* q   = (const float*)d_in[0];
  const float* k   = (const float*)d_in[1];
  const float* v   = (const float*)d_in[2];
  const float* Wi  = (const float*)d_in[3];
  const float* bi  = (const float*)d_in[4];
  const float* Wg  = (const float*)d_in[5];
  const float* bg  = (const float*)d_in[6];
  const float* A   = (const float*)d_in[7];
  const float* Bm  = (const float*)d_in[8];
  const float* Wo  = (const float*)d_in[9];
  const float* bo  = (const float*)d_in[10];
  const float* dec = (const float*)d_in[11];

  size_t need = (4*BIGN + 2*(size_t)64*4096)*sizeof(float) + SEQ*sizeof(int);
  if (ws_size < need) return;

  float* b0 = (float*)d_ws;          // ret -> u -> s
  float* b1 = b0 + BIGN;             // inp
  float* b2 = b1 + BIGN;             // g
  float* b3 = b2 + BIGN;             // d  (pre-activation constant)
  float* E     = b3 + BIGN;
  float* carry = E + (size_t)64*4096;
  int*   ctr   = (int*)(carry + (size_t)64*4096);
  float* outp  = (float*)d_out;

  hipMemsetAsync(ctr, 0, SEQ*sizeof(int), stream);

  scan_a<<<1024, 256, 0, stream>>>(k, v, dec, E);
  scan_b<<<16,   256, 0, stream>>>(E, dec, carry);
  scan_c<<<1024, 256, 0, stream>>>(q, k, v, dec, carry, b0);

  dim3 gg(DIM/GN, MROWS/GM);
  gemm_k<0><<<gg, 256, 0, stream>>>(b0, Wi, bi, b1, nullptr, nullptr, nullptr); // inp
  gemm_k<1><<<gg, 256, 0, stream>>>(b1, Wg, bg, b2, b1, b0, nullptr);           // g, u
  gemm_k<4><<<gg, 256, 0, stream>>>(b0, A,  nullptr, b3, nullptr, nullptr, nullptr); // d  = u@A^T
  gemm_k<2><<<gg, 256, 0, stream>>>(b1, Bm, nullptr, b3, nullptr, nullptr, nullptr); // d += inp@Bm^T

  recur_k<<<RG, 256, 0, stream>>>(A, b2, b3, b0, ctr);                          // s

  gemm_k<3><<<gg, 256, 0, stream>>>(b0, Wo, bo, nullptr, nullptr, nullptr, outp); // out
}

// Round 5
// 8958.693 us; speedup vs baseline: 3.2405x; 3.2405x over previous
//
#include <hip/hip_runtime.h>
#include <hip/hip_bf16.h>
#include <math.h>

#define BATCH 4
#define SEQ   2048
#define DIM   1024
#define MROWS (SEQ*BATCH)          // 8192
#define BIGN  ((size_t)MROWS*DIM)  // 8388608 floats per buffer

// ---------------- chunked scan for r_t = dec*r + k*v,  ret = q*r --------------
__global__ __launch_bounds__(256) void scan_a(const float* __restrict__ K,
    const float* __restrict__ V, const float* __restrict__ dec_p,
    float* __restrict__ E)
{
  int id  = blockIdx.x*256 + threadIdx.x;   // 0..262143
  int c   = id >> 12;
  int rem = id & 4095;
  int b   = rem >> 10;
  int dc  = rem & 1023;
  float dec = dec_p[dc >> 6];
  size_t base = ((size_t)b*SEQ + (size_t)c*32)*DIM + dc;
  float r = 0.f;
  #pragma unroll 4
  for (int i = 0; i < 32; ++i) {
    float kv = K[base + (size_t)i*DIM] * V[base + (size_t)i*DIM];
    r = fmaf(dec, r, kv);
  }
  E[(size_t)c*4096 + rem] = r;
}

__global__ __launch_bounds__(256) void scan_b(const float* __restrict__ E,
    const float* __restrict__ dec_p, float* __restrict__ carry)
{
  int id = blockIdx.x*256 + threadIdx.x;    // 0..4095
  int dc = id & 1023;
  float dec = dec_p[dc >> 6];
  float d2 = dec*dec, d4 = d2*d2, d8 = d4*d4, d16 = d8*d8, d32 = d16*d16;
  float r = 0.f;
  #pragma unroll 1
  for (int c = 0; c < 64; ++c) {
    carry[(size_t)c*4096 + id] = r;
    r = fmaf(d32, r, E[(size_t)c*4096 + id]);
  }
}

__global__ __launch_bounds__(256) void scan_c(const float* __restrict__ Q,
    const float* __restrict__ K, const float* __restrict__ V,
    const float* __restrict__ dec_p, const float* __restrict__ carry,
    float* __restrict__ ret)
{
  int id  = blockIdx.x*256 + threadIdx.x;
  int c   = id >> 12;
  int rem = id & 4095;
  int b   = rem >> 10;
  int dc  = rem & 1023;
  float dec = dec_p[dc >> 6];
  size_t base = ((size_t)b*SEQ + (size_t)c*32)*DIM + dc;
  float r = carry[(size_t)c*4096 + rem];
  #pragma unroll 1
  for (int i = 0; i < 32; ++i) {
    int t = c*32 + i;
    float kv = K[base + (size_t)i*DIM] * V[base + (size_t)i*DIM];
    r = fmaf(dec, r, kv);
    ret[((size_t)t*BATCH + b)*DIM + dc] = Q[base + (size_t)i*DIM] * r;
  }
}

// ---------------- fp32 tiled GEMM: C[m,n] = sum_k X[m,k]*W[n,k] (+bias) -------
// MODE 0: C = XW^T + bias
// MODE 1: g = sigmoid(XW^T + bias) -> C;  u_out = (1-g)*inp
// MODE 2: C += XW^T
// MODE 3: outf[b,t,n] = XW^T + bias   (m = t*4+b scatter), float32 output
// MODE 4: C = XW^T
#define GM 64
#define GN 64
#define GK 32
#define LDA 68

template<int MODE>
__global__ __launch_bounds__(256) void gemm_k(
    const float* __restrict__ X, const float* __restrict__ W,
    const float* __restrict__ bias, float* __restrict__ C,
    const float* __restrict__ inp, float* __restrict__ u_out,
    float* __restrict__ outf)
{
  __shared__ float Xs[GK][LDA];
  __shared__ float Ws[GK][LDA];
  const int tid = threadIdx.x;
  const int m0 = blockIdx.y * GM;
  const int n0 = blockIdx.x * GN;
  const int tx = tid & 15, ty = tid >> 4;
  float acc[4][4] = {};
  #pragma unroll 1
  for (int kb = 0; kb < DIM; kb += GK) {
    #pragma unroll
    for (int h = 0; h < 2; ++h) {
      int idx = tid + h*256;
      int row = idx >> 3;        // 0..63
      int kc  = (idx & 7) << 2;  // 0,4,...,28
      float4 xv = *(const float4*)(X + (size_t)(m0+row)*DIM + kb + kc);
      Xs[kc+0][row] = xv.x; Xs[kc+1][row] = xv.y;
      Xs[kc+2][row] = xv.z; Xs[kc+3][row] = xv.w;
      float4 wv = *(const float4*)(W + (size_t)(n0+row)*DIM + kb + kc);
      Ws[kc+0][row] = wv.x; Ws[kc+1][row] = wv.y;
      Ws[kc+2][row] = wv.z; Ws[kc+3][row] = wv.w;
    }
    __syncthreads();
    #pragma unroll
    for (int kk = 0; kk < GK; ++kk) {
      float4 a = *(const float4*)&Xs[kk][ty << 2];
      float4 w = *(const float4*)&Ws[kk][tx << 2];
      float av[4] = {a.x, a.y, a.z, a.w};
      float wv[4] = {w.x, w.y, w.z, w.w};
      #pragma unroll
      for (int i = 0; i < 4; ++i)
        #pragma unroll
        for (int j = 0; j < 4; ++j)
          acc[i][j] = fmaf(av[i], wv[j], acc[i][j]);
    }
    __syncthreads();
  }
  float bj[4];
  #pragma unroll
  for (int j = 0; j < 4; ++j)
    bj[j] = (MODE == 0 || MODE == 1 || MODE == 3) ? bias[n0 + (tx<<2) + j] : 0.f;
  #pragma unroll
  for (int i = 0; i < 4; ++i) {
    int m = m0 + (ty<<2) + i;
    #pragma unroll
    for (int j = 0; j < 4; ++j) {
      int n = n0 + (tx<<2) + j;
      size_t off = (size_t)m*DIM + n;
      float vv = acc[i][j] + bj[j];
      if (MODE == 2) vv += C[off];
      if (MODE == 1) {
        float gv = 1.f/(1.f + expf(-vv));
        C[off] = gv;
        u_out[off] = (1.f - gv) * inp[off];
      } else if (MODE == 3) {
        outf[((size_t)(m & 3)*SEQ + (size_t)(m >> 2))*DIM + n] = vv;
      } else {
        C[off] = vv;
      }
    }
  }
}

// ---------------- sequential recurrence: s_t = tanh((g_t*s_{t-1})@A^T + d_t) --
// 4 independent batch chains. Per batch: 16 blocks x 512 threads, each block
// owns 64 rows of A in registers (8 lanes/row, k split 8x128). Per-batch
// counters (64B-strided lines), block-level release publish (16 RMW/step),
// block-shared staging: s loaded ONCE per block (4KB, relaxed agent atomics
// -> L3, no fences), x = g*s in slice-padded LDS (132-float stride: the
// 8-address broadcast b128 read covers all 32 banks conflict-free).
#define RBLK 64

__global__ __launch_bounds__(512, 2) void recur_k(
    const float* __restrict__ A, const float* __restrict__ g,
    const float* __restrict__ dpre, float* __restrict__ s,
    int* __restrict__ ctr)
{
  __shared__ __align__(16) float xs[8*132 + 4];   // 4240 B
  const int tid = threadIdx.x;
  const int w   = tid >> 6;                 // wave 0..7
  const int ln  = tid & 63;
  const int b   = blockIdx.x >> 4;          // batch 0..3
  const int blk = blockIdx.x & 15;          // block within batch
  const int row = blk*64 + w*8 + (ln >> 3); // global row 0..1023
  const int ks  = ln & 7;                   // k-slice (128 floats)
  int* cbase = ctr + (size_t)b*SEQ*16;

  // A fragment: (row, k in [ks*128, ks*128+128))
  float4 areg[32];
  #pragma unroll
  for (int j = 0; j < 32; ++j)
    areg[j] = *(const float4*)(A + (size_t)row*DIM + ks*128 + 4*j);

  // x-staging slot for this thread: floats [2*tid, 2*tid+1] of x
  const int xoff = (tid >> 6)*132 + ((2*tid) & 127);

  #pragma unroll 1
  for (int t = 0; t < SEQ; ++t) {
    // prefetches (flag-independent -> issue before the spin)
    float2 gv = *(const float2*)(g + ((size_t)t*4 + b)*DIM + 2*tid);
    float dval = (ks == 0) ? dpre[((size_t)t*4 + b)*DIM + row] : 0.f;

    float acc0 = 0.f, acc1 = 0.f, acc2 = 0.f, acc3 = 0.f;
    if (t > 0) {
      // spin until all 16 blocks of this batch published step t-1
      int done = 0, guard = 0;
      while (!done) {
        int c = 0;
        if (ln == 0)
          c = __hip_atomic_load(cbase + (size_t)(t-1)*16, __ATOMIC_RELAXED,
                                __HIP_MEMORY_SCOPE_AGENT);
        c = __shfl(c, 0, 64);
        done = (c >= 16) | (++guard > (1 << 24));
      }
      __asm__ __volatile__("" ::: "memory");

      // stage x = g * s[t-1][b] : one float2 per thread (4KB/block total)
      union { unsigned long long u; float f[2]; } sv;
      sv.u = __hip_atomic_load(
          (const unsigned long long*)(s + ((size_t)(t-1)*4 + b)*DIM) + tid,
          __ATOMIC_RELAXED, __HIP_MEMORY_SCOPE_AGENT);
      *(float2*)(xs + xoff) = make_float2(gv.x*sv.f[0], gv.y*sv.f[1]);
      __syncthreads();

      // matvec: this lane covers k-slice ks of its row
      const float* xb = xs + ks*132;
      #pragma unroll
      for (int j = 0; j < 32; j += 4) {
        float4 x0 = *(const float4*)(xb + 4*j);
        float4 x1 = *(const float4*)(xb + 4*j + 4);
        float4 x2 = *(const float4*)(xb + 4*j + 8);
        float4 x3 = *(const float4*)(xb + 4*j + 12);
        acc0 = fmaf(areg[j+0].x, x0.x, fmaf(areg[j+0].y, x0.y,
               fmaf(areg[j+0].z, x0.z, fmaf(areg[j+0].w, x0.w, acc0))));
        acc1 = fmaf(areg[j+1].x, x1.x, fmaf(areg[j+1].y, x1.y,
               fmaf(areg[j+1].z, x1.z, fmaf(areg[j+1].w, x1.w, acc1))));
        acc2 = fmaf(areg[j+2].x, x2.x, fmaf(areg[j+2].y, x2.y,
               fmaf(areg[j+2].z, x2.z, fmaf(areg[j+2].w, x2.w, acc2))));
        acc3 = fmaf(areg[j+3].x, x3.x, fmaf(areg[j+3].y, x3.y,
               fmaf(areg[j+3].z, x3.z, fmaf(areg[j+3].w, x3.w, acc3))));
      }
    }
    float sum = (acc0 + acc1) + (acc2 + acc3);
    // reduce over the 8 k-slice lanes of this row
    sum += __shfl_xor(sum, 1, 64);
    sum += __shfl_xor(sum, 2, 64);
    sum += __shfl_xor(sum, 4, 64);
    if (ks == 0) {
      float val = tanhf(sum + dval);
      __hip_atomic_store(s + ((size_t)t*4 + b)*DIM + row, val,
                         __ATOMIC_RELAXED, __HIP_MEMORY_SCOPE_AGENT);
    }
    __syncthreads();   // drains all waves' stores; also protects xs reuse
    if (tid == 0)
      __hip_atomic_fetch_add(cbase + (size_t)t*16, 1, __ATOMIC_RELEASE,
                             __HIP_MEMORY_SCOPE_AGENT);
  }
}

// ------------------------------------------------------------------------------
extern "C" void kernel_launch(void* const* d_in, const int* in_sizes, int n_in,
                              void* d_out, int out_size, void* d_ws, size_t ws_size,
                              hipStream_t stream)
{
  (void)in_sizes; (void)n_in; (void)out_size;
  const float* q   = (const float*)d_in[0];
  const float* k   = (const float*)d_in[1];
  const float* v   = (const float*)d_in[2];
  const float* Wi  = (const float*)d_in[3];
  const float* bi  = (const float*)d_in[4];
  const float* Wg  = (const float*)d_in[5];
  const float* bg  = (const float*)d_in[6];
  const float* A   = (const float*)d_in[7];
  const float* Bm  = (const float*)d_in[8];
  const float* Wo  = (const float*)d_in[9];
  const float* bo  = (const float*)d_in[10];
  const float* dec = (const float*)d_in[11];

  const size_t ctr_n = (size_t)BATCH*SEQ*16;   // ints
  size_t need = (4*BIGN + 2*(size_t)64*4096)*sizeof(float) + ctr_n*sizeof(int);
  if (ws_size < need) return;

  float* b0 = (float*)d_ws;          // ret -> u -> s
  float* b1 = b0 + BIGN;             // inp
  float* b2 = b1 + BIGN;             // g
  float* b3 = b2 + BIGN;             // d  (pre-activation constant)
  float* E     = b3 + BIGN;
  float* carry = E + (size_t)64*4096;
  int*   ctr   = (int*)(carry + (size_t)64*4096);
  float* outp  = (float*)d_out;

  hipMemsetAsync(ctr, 0, ctr_n*sizeof(int), stream);

  scan_a<<<1024, 256, 0, stream>>>(k, v, dec, E);
  scan_b<<<16,   256, 0, stream>>>(E, dec, carry);
  scan_c<<<1024, 256, 0, stream>>>(q, k, v, dec, carry, b0);

  dim3 gg(DIM/GN, MROWS/GM);
  gemm_k<0><<<gg, 256, 0, stream>>>(b0, Wi, bi, b1, nullptr, nullptr, nullptr); // inp
  gemm_k<1><<<gg, 256, 0, stream>>>(b1, Wg, bg, b2, b1, b0, nullptr);           // g, u
  gemm_k<4><<<gg, 256, 0, stream>>>(b0, A,  nullptr, b3, nullptr, nullptr, nullptr); // d  = u@A^T
  gemm_k<2><<<gg, 256, 0, stream>>>(b1, Bm, nullptr, b3, nullptr, nullptr, nullptr); // d += inp@Bm^T

  recur_k<<<RBLK, 512, 0, stream>>>(A, b2, b3, b0, ctr);                        // s

  gemm_k<3><<<gg, 256, 0, stream>>>(b0, Wo, bo, nullptr, nullptr, nullptr, outp); // out
}